// Round 1
// baseline (1797.606 us; speedup 1.0000x reference)
//
#include <hip/hip_runtime.h>
#include <cstdint>
#include <cstddef>

#define B_     4
#define L_     5000
#define H_     256
#define W_     256
#define HW_    65536
#define CIN_   256
#define DLOI_  128
#define NPTS0_ 32
#define NPTS1_ 8
#define DFC_   1024
#define NOUT_  2500
#define M_     (B_*L_)   // 20000

// ---------------------------------------------------------------------------
// K1: 1x1 conv  x[b][p][o] = sum_c feature[b][c][p] * fc1_w[o][c] + fc1_b[o]
// tile: 64 p x 128 o, 256 threads, thread = 4p x 8o
// ---------------------------------------------------------------------------
__global__ __launch_bounds__(256) void k_conv(const float* __restrict__ fin,
                                              const float* __restrict__ w,
                                              const float* __restrict__ bias,
                                              float* __restrict__ xout) {
  __shared__ float sA[16][64];    // [kk][p]
  __shared__ float sW[128][16];   // [o][kk]
  const int t = threadIdx.x;
  const int p0 = blockIdx.x * 64;
  const int b  = blockIdx.y;
  const int tp = t & 15;          // p group (4 p each)
  const int to = t >> 4;          // o group (8 o each)
  float acc[4][8];
  #pragma unroll
  for (int i = 0; i < 4; i++)
    #pragma unroll
    for (int j = 0; j < 8; j++) acc[i][j] = 0.f;

  const float* fb = fin + (size_t)b * CIN_ * HW_;
  for (int c0 = 0; c0 < CIN_; c0 += 16) {
    { // stage A: 16 c-rows x 64 p, one float4 per thread
      int kk = t >> 4, f4 = t & 15;
      float4 v = *(const float4*)(fb + (size_t)(c0 + kk) * HW_ + p0 + f4 * 4);
      *(float4*)(&sA[kk][f4 * 4]) = v;
    }
    { // stage W: 128 o x 16 kk  (consecutive threads read consecutive c)
      #pragma unroll
      for (int i = 0; i < 8; i++) {
        int idx = t + i * 256;
        int o = idx >> 4, kk = idx & 15;
        sW[o][kk] = w[o * CIN_ + c0 + kk];
      }
    }
    __syncthreads();
    #pragma unroll
    for (int kk = 0; kk < 16; kk++) {
      float a[4], wv[8];
      #pragma unroll
      for (int i = 0; i < 4; i++) a[i] = sA[kk][tp * 4 + i];
      #pragma unroll
      for (int j = 0; j < 8; j++) wv[j] = sW[to * 8 + j][kk];
      #pragma unroll
      for (int i = 0; i < 4; i++)
        #pragma unroll
        for (int j = 0; j < 8; j++) acc[i][j] = fmaf(a[i], wv[j], acc[i][j]);
    }
    __syncthreads();
  }
  float bj[8];
  #pragma unroll
  for (int j = 0; j < 8; j++) bj[j] = bias[to * 8 + j];
  #pragma unroll
  for (int i = 0; i < 4; i++) {
    float* dst = xout + ((size_t)b * HW_ + p0 + tp * 4 + i) * DLOI_ + to * 8;
    float4 v0 = make_float4(acc[i][0] + bj[0], acc[i][1] + bj[1],
                            acc[i][2] + bj[2], acc[i][3] + bj[3]);
    float4 v1 = make_float4(acc[i][4] + bj[4], acc[i][5] + bj[5],
                            acc[i][6] + bj[6], acc[i][7] + bj[7]);
    *(float4*)(dst)     = v0;
    *(float4*)(dst + 4) = v1;
  }
}

// ---------------------------------------------------------------------------
// K2: sample 32 pts/line, bilinear on x (channel-last), maxpool by 4
// feat[b*L+l][c*8+q].  One block per line, 128 threads (one per channel).
// ---------------------------------------------------------------------------
__global__ __launch_bounds__(128) void k_sample(const float* __restrict__ x,
                                                const float* __restrict__ lines,
                                                float* __restrict__ feat) {
  const int blk = blockIdx.x;   // b*L + l
  const int b = blk / L_;
  const int c = threadIdx.x;
  const float* ln = lines + (size_t)blk * 4;
  const float e0x = ln[0], e0y = ln[1], e1x = ln[2], e1y = ln[3];
  const float* xb = x + (size_t)b * HW_ * DLOI_;
  float* frow = feat + (size_t)blk * (DLOI_ * NPTS1_);
  for (int q = 0; q < NPTS1_; q++) {
    float m = -1e30f;
    #pragma unroll
    for (int r = 0; r < 4; r++) {
      int i = q * 4 + r;
      float lam = (float)i * (1.0f / 31.0f);
      float px = e0x * lam + e1x * (1.f - lam) - 0.5f;
      float py = e0y * lam + e1y * (1.f - lam) - 0.5f;
      float px0 = fminf(fmaxf(floorf(px), 0.f), 255.f);
      float py0 = fminf(fmaxf(floorf(py), 0.f), 255.f);
      float px1 = fminf(px0 + 1.f, 255.f);
      float py1 = fminf(py0 + 1.f, 255.f);
      int ix0 = (int)px0, iy0 = (int)py0, ix1 = (int)px1, iy1 = (int)py1;
      float w00 = (px1 - px) * (py1 - py);
      float w10 = (px - px0) * (py1 - py);
      float w01 = (px1 - px) * (py - py0);
      float w11 = (px - px0) * (py - py0);
      float v = w00 * xb[(size_t)(ix0 * W_ + iy0) * DLOI_ + c]
              + w10 * xb[(size_t)(ix1 * W_ + iy0) * DLOI_ + c]
              + w01 * xb[(size_t)(ix0 * W_ + iy1) * DLOI_ + c]
              + w11 * xb[(size_t)(ix1 * W_ + iy1) * DLOI_ + c];
      m = fmaxf(m, v);
    }
    frow[c * NPTS1_ + q] = m;
  }
}

// ---------------------------------------------------------------------------
// K3/K4: fp32 GEMM  out = [relu](A[M][K] @ Wm[K][N] + bias), tile 128x128
// ---------------------------------------------------------------------------
template <bool RELU>
__global__ __launch_bounds__(256) void k_gemm(const float* __restrict__ A,
                                              const float* __restrict__ Wm,
                                              const float* __restrict__ bias,
                                              float* __restrict__ out,
                                              int M, int N, int K) {
  __shared__ float sA[8][128];   // [kk][m]
  __shared__ float sB[8][128];   // [kk][n]
  const int t = threadIdx.x;
  const int n0 = blockIdx.x * 128;
  const int r0 = blockIdx.y * 128;
  const int tm = t & 15, tn = t >> 4;
  float acc[8][8];
  #pragma unroll
  for (int i = 0; i < 8; i++)
    #pragma unroll
    for (int j = 0; j < 8; j++) acc[i][j] = 0.f;

  for (int k0 = 0; k0 < K; k0 += 8) {
    { // stage A: float4 per thread
      int m = t & 127, h = t >> 7;
      float4 v = make_float4(0.f, 0.f, 0.f, 0.f);
      int row = r0 + m;
      if (row < M) v = *(const float4*)(A + (size_t)row * K + k0 + h * 4);
      sA[h * 4 + 0][m] = v.x;
      sA[h * 4 + 1][m] = v.y;
      sA[h * 4 + 2][m] = v.z;
      sA[h * 4 + 3][m] = v.w;
    }
    { // stage B: float4 per thread, coalesced along n
      int kk = t >> 5, n4 = t & 31;
      float4 v = *(const float4*)(Wm + (size_t)(k0 + kk) * N + n0 + n4 * 4);
      *(float4*)(&sB[kk][n4 * 4]) = v;
    }
    __syncthreads();
    #pragma unroll
    for (int kk = 0; kk < 8; kk++) {
      float a[8], bv[8];
      #pragma unroll
      for (int i = 0; i < 8; i++) a[i] = sA[kk][tm * 8 + i];
      #pragma unroll
      for (int j = 0; j < 8; j++) bv[j] = sB[kk][tn * 8 + j];
      #pragma unroll
      for (int i = 0; i < 8; i++)
        #pragma unroll
        for (int j = 0; j < 8; j++) acc[i][j] = fmaf(a[i], bv[j], acc[i][j]);
    }
    __syncthreads();
  }
  float bj[8];
  #pragma unroll
  for (int j = 0; j < 8; j++) bj[j] = bias[n0 + tn * 8 + j];
  #pragma unroll
  for (int i = 0; i < 8; i++) {
    int row = r0 + tm * 8 + i;
    if (row < M) {
      float v[8];
      #pragma unroll
      for (int j = 0; j < 8; j++) {
        v[j] = acc[i][j] + bj[j];
        if (RELU) v[j] = fmaxf(v[j], 0.f);
      }
      float* dst = out + (size_t)row * N + n0 + tn * 8;
      *(float4*)(dst)     = make_float4(v[0], v[1], v[2], v[3]);
      *(float4*)(dst + 4) = make_float4(v[4], v[5], v[6], v[7]);
    }
  }
}

// ---------------------------------------------------------------------------
// K5: logits = h2 @ w3 + b3, softmax, keep/argmax key.  One wave per row.
// ---------------------------------------------------------------------------
__global__ __launch_bounds__(256) void k_head(const float* __restrict__ h2,
                                              const float* __restrict__ w3,
                                              const float* __restrict__ b3,
                                              float* __restrict__ s_out,
                                              int* __restrict__ key_out) {
  const int wave = threadIdx.x >> 6;
  const int lane = threadIdx.x & 63;
  const int row = blockIdx.x * 4 + wave;
  if (row >= M_) return;
  const float* hr = h2 + (size_t)row * DFC_;
  float a0 = 0.f, a1 = 0.f, a2 = 0.f, a3 = 0.f;
  for (int k = lane; k < DFC_; k += 64) {
    float hv = hr[k];
    float4 wv = *(const float4*)(w3 + k * 4);
    a0 = fmaf(hv, wv.x, a0);
    a1 = fmaf(hv, wv.y, a1);
    a2 = fmaf(hv, wv.z, a2);
    a3 = fmaf(hv, wv.w, a3);
  }
  #pragma unroll
  for (int off = 32; off >= 1; off >>= 1) {
    a0 += __shfl_down(a0, off);
    a1 += __shfl_down(a1, off);
    a2 += __shfl_down(a2, off);
    a3 += __shfl_down(a3, off);
  }
  if (lane == 0) {
    float l0 = a0 + b3[0], l1 = a1 + b3[1], l2 = a2 + b3[2], l3 = a3 + b3[3];
    float mx = fmaxf(fmaxf(l0, l1), fmaxf(l2, l3));
    float e0 = expf(l0 - mx), e1 = expf(l1 - mx), e2 = expf(l2 - mx), e3 = expf(l3 - mx);
    float inv = 1.f / (e0 + e1 + e2 + e3);
    float s0 = e0 * inv, s1 = e1 * inv, s2 = e2 * inv, s3 = e3 * inv;
    *(float4*)(s_out + (size_t)row * 4) = make_float4(s0, s1, s2, s3);
    bool keep = ((s1 > 0.25f) || (s2 > 0.25f) || (s3 > 0.25f)) && (s0 < 0.25f);
    int am = 0; float best = s0;
    if (s1 > best) { best = s1; am = 1; }
    if (s2 > best) { best = s2; am = 2; }
    if (s3 > best) { best = s3; am = 3; }
    key_out[row] = keep ? am : -1;
  }
}

// ---------------------------------------------------------------------------
// K6: per-batch stable counting sort (5 classes) + cyclic select.
// One block (1024 thr) per batch; thread t owns lines [5t, 5t+5).
// ---------------------------------------------------------------------------
__global__ __launch_bounds__(1024) void k_select(const int* __restrict__ key,
                                                 const float* __restrict__ lines,
                                                 const float* __restrict__ s,
                                                 float* __restrict__ out_lines,
                                                 float* __restrict__ out_score) {
  __shared__ int s_ord[L_];
  __shared__ int s_scan[1024];
  __shared__ int s_tot[5];
  const int b = blockIdx.x;
  const int t = threadIdx.x;
  const int base_l = t * 5;
  int cls[5];
  int c[5] = {0, 0, 0, 0, 0};
  #pragma unroll
  for (int i = 0; i < 5; i++) {
    int l = base_l + i;
    int cl = -1;
    if (l < L_) {
      int k = key[b * L_ + l];
      cl = (k < 0) ? 4 : (3 - k);   // key 3->0, 2->1, 1->2, 0->3, -1->4
      c[cl]++;
    }
    cls[i] = cl;
  }
  int pf[5];
  for (int cc = 0; cc < 5; cc++) {
    s_scan[t] = c[cc];
    __syncthreads();
    for (int off = 1; off < 1024; off <<= 1) {
      int add = (t >= off) ? s_scan[t - off] : 0;
      __syncthreads();
      s_scan[t] += add;
      __syncthreads();
    }
    pf[cc] = s_scan[t] - c[cc];              // exclusive prefix over threads
    if (t == 1023) s_tot[cc] = s_scan[1023]; // class total
    __syncthreads();
  }
  int basec[5];
  basec[0] = 0;
  #pragma unroll
  for (int cc = 1; cc < 5; cc++) basec[cc] = basec[cc - 1] + s_tot[cc - 1];
  int run[5] = {0, 0, 0, 0, 0};
  #pragma unroll
  for (int i = 0; i < 5; i++) {
    if (cls[i] >= 0) {
      int cl = cls[i];
      int pos = basec[cl] + pf[cl] + run[cl];
      run[cl]++;
      s_ord[pos] = base_l + i;
    }
  }
  const int cnt = L_ - s_tot[4];
  __syncthreads();
  for (int j = t; j < NOUT_; j += 1024) {
    float4 lv = make_float4(0.f, 0.f, 0.f, 0.f);
    float4 sv = make_float4(0.f, 0.f, 0.f, 0.f);
    if (cnt > 0) {
      int idx = s_ord[j % cnt];
      lv = *(const float4*)(lines + (size_t)(b * L_ + idx) * 4);
      sv = *(const float4*)(s + (size_t)(b * L_ + idx) * 4);
    }
    *(float4*)(out_lines + (size_t)(b * NOUT_ + j) * 4) = lv;
    *(float4*)(out_score + (size_t)(b * NOUT_ + j) * 4) = sv;
  }
}

// ---------------------------------------------------------------------------
extern "C" void kernel_launch(void* const* d_in, const int* in_sizes, int n_in,
                              void* d_out, int out_size, void* d_ws, size_t ws_size,
                              hipStream_t stream) {
  const float* feature = (const float*)d_in[0];
  const float* lines   = (const float*)d_in[1];
  const float* fc1_w   = (const float*)d_in[2];
  const float* fc1_b   = (const float*)d_in[3];
  const float* w1      = (const float*)d_in[4];
  const float* b1      = (const float*)d_in[5];
  const float* w2      = (const float*)d_in[6];
  const float* b2      = (const float*)d_in[7];
  const float* w3      = (const float*)d_in[8];
  const float* b3      = (const float*)d_in[9];

  float* out_lines = (float*)d_out;                 // [4][2500][2][2]
  float* out_score = out_lines + B_ * NOUT_ * 4;    // [4][2500][4]
  float* s_out     = out_score + B_ * NOUT_ * 4;    // [4][5000][4]

  // workspace layout (bytes):
  //   x    : 0                     134,217,728  (4*65536*128 fp32, channel-last)
  //   feat : 134,217,728            81,920,000  (20000 x 1024 fp32)
  //   h1   : 216,137,728            81,920,000
  //   h2   : reuse x region (x dead after k_sample)
  //   keys : 298,057,728                80,000
  char* ws = (char*)d_ws;
  float* x    = (float*)(ws);
  float* feat = (float*)(ws + 134217728);
  float* h1   = (float*)(ws + 134217728 + 81920000);
  float* h2   = x;
  int*   keys = (int*)(ws + 134217728 + (size_t)2 * 81920000);

  k_conv<<<dim3(HW_ / 64, B_), 256, 0, stream>>>(feature, fc1_w, fc1_b, x);
  k_sample<<<dim3(M_), 128, 0, stream>>>(x, lines, feat);
  k_gemm<true><<<dim3(DFC_ / 128, (M_ + 127) / 128), 256, 0, stream>>>(
      feat, w1, b1, h1, M_, DFC_, DFC_);
  k_gemm<true><<<dim3(DFC_ / 128, (M_ + 127) / 128), 256, 0, stream>>>(
      h1, w2, b2, h2, M_, DFC_, DFC_);
  k_head<<<dim3(M_ / 4), 256, 0, stream>>>(h2, w3, b3, s_out, keys);
  k_select<<<dim3(B_), 1024, 0, stream>>>(keys, lines, s_out, out_lines, out_score);
}

// Round 2
// 1123.343 us; speedup vs baseline: 1.6002x; 1.6002x over previous
//
#include <hip/hip_runtime.h>
#include <cstdint>
#include <cstddef>

#define B_     4
#define L_     5000
#define H_     256
#define W_     256
#define HW_    65536
#define CIN_   256
#define DLOI_  128
#define NPTS0_ 32
#define NPTS1_ 8
#define DFC_   1024
#define NOUT_  2500
#define M_     (B_*L_)   // 20000
#define MPAD_  20096     // 157 * 128

typedef _Float16 f16;
typedef _Float16 f16x8 __attribute__((ext_vector_type(8)));
typedef float    f32x4 __attribute__((ext_vector_type(4)));

__device__ __forceinline__ void gload16(const void* g, void* l) {
  __builtin_amdgcn_global_load_lds(
      (const __attribute__((address_space(1))) void*)g,
      (__attribute__((address_space(3))) void*)l, 16, 0, 0);
}

// ---------------------------------------------------------------------------
// K1: 1x1 conv  x[b][p][o] = sum_c feature[b][c][p] * fc1_w[o][c] + fc1_b[o]
// fp32 VALU, tile 64p x 128o (unchanged this round)
// ---------------------------------------------------------------------------
__global__ __launch_bounds__(256) void k_conv(const float* __restrict__ fin,
                                              const float* __restrict__ w,
                                              const float* __restrict__ bias,
                                              float* __restrict__ xout) {
  __shared__ float sA[16][64];
  __shared__ float sW[128][16];
  const int t = threadIdx.x;
  const int p0 = blockIdx.x * 64;
  const int b  = blockIdx.y;
  const int tp = t & 15;
  const int to = t >> 4;
  float acc[4][8];
  #pragma unroll
  for (int i = 0; i < 4; i++)
    #pragma unroll
    for (int j = 0; j < 8; j++) acc[i][j] = 0.f;

  const float* fb = fin + (size_t)b * CIN_ * HW_;
  for (int c0 = 0; c0 < CIN_; c0 += 16) {
    {
      int kk = t >> 4, f4 = t & 15;
      float4 v = *(const float4*)(fb + (size_t)(c0 + kk) * HW_ + p0 + f4 * 4);
      *(float4*)(&sA[kk][f4 * 4]) = v;
    }
    {
      #pragma unroll
      for (int i = 0; i < 8; i++) {
        int idx = t + i * 256;
        int o = idx >> 4, kk = idx & 15;
        sW[o][kk] = w[o * CIN_ + c0 + kk];
      }
    }
    __syncthreads();
    #pragma unroll
    for (int kk = 0; kk < 16; kk++) {
      float a[4], wv[8];
      #pragma unroll
      for (int i = 0; i < 4; i++) a[i] = sA[kk][tp * 4 + i];
      #pragma unroll
      for (int j = 0; j < 8; j++) wv[j] = sW[to * 8 + j][kk];
      #pragma unroll
      for (int i = 0; i < 4; i++)
        #pragma unroll
        for (int j = 0; j < 8; j++) acc[i][j] = fmaf(a[i], wv[j], acc[i][j]);
    }
    __syncthreads();
  }
  float bj[8];
  #pragma unroll
  for (int j = 0; j < 8; j++) bj[j] = bias[to * 8 + j];
  #pragma unroll
  for (int i = 0; i < 4; i++) {
    float* dst = xout + ((size_t)b * HW_ + p0 + tp * 4 + i) * DLOI_ + to * 8;
    *(float4*)(dst)     = make_float4(acc[i][0] + bj[0], acc[i][1] + bj[1],
                                      acc[i][2] + bj[2], acc[i][3] + bj[3]);
    *(float4*)(dst + 4) = make_float4(acc[i][4] + bj[4], acc[i][5] + bj[5],
                                      acc[i][6] + bj[6], acc[i][7] + bj[7]);
  }
}

// ---------------------------------------------------------------------------
// K2: sample 32 pts/line, bilinear, maxpool by 4 -> feat as f16 hi/lo planes
// feat row layout: [c*8+q], one block per line, 128 threads (one per channel)
// ---------------------------------------------------------------------------
__global__ __launch_bounds__(128) void k_sample(const float* __restrict__ x,
                                                const float* __restrict__ lines,
                                                f16* __restrict__ fh,
                                                f16* __restrict__ fl) {
  const int blk = blockIdx.x;   // b*L + l
  const int b = blk / L_;
  const int c = threadIdx.x;
  const float* ln = lines + (size_t)blk * 4;
  const float e0x = ln[0], e0y = ln[1], e1x = ln[2], e1y = ln[3];
  const float* xb = x + (size_t)b * HW_ * DLOI_;
  f16x8 vh, vl;
  for (int q = 0; q < NPTS1_; q++) {
    float m = -1e30f;
    #pragma unroll
    for (int r = 0; r < 4; r++) {
      int i = q * 4 + r;
      float lam = (float)i * (1.0f / 31.0f);
      float px = e0x * lam + e1x * (1.f - lam) - 0.5f;
      float py = e0y * lam + e1y * (1.f - lam) - 0.5f;
      float px0 = fminf(fmaxf(floorf(px), 0.f), 255.f);
      float py0 = fminf(fmaxf(floorf(py), 0.f), 255.f);
      float px1 = fminf(px0 + 1.f, 255.f);
      float py1 = fminf(py0 + 1.f, 255.f);
      int ix0 = (int)px0, iy0 = (int)py0, ix1 = (int)px1, iy1 = (int)py1;
      float w00 = (px1 - px) * (py1 - py);
      float w10 = (px - px0) * (py1 - py);
      float w01 = (px1 - px) * (py - py0);
      float w11 = (px - px0) * (py - py0);
      float v = w00 * xb[(size_t)(ix0 * W_ + iy0) * DLOI_ + c]
              + w10 * xb[(size_t)(ix1 * W_ + iy0) * DLOI_ + c]
              + w01 * xb[(size_t)(ix0 * W_ + iy1) * DLOI_ + c]
              + w11 * xb[(size_t)(ix1 * W_ + iy1) * DLOI_ + c];
      m = fmaxf(m, v);
    }
    f16 h = (f16)m;
    vh[q] = h;
    vl[q] = (f16)(m - (float)h);
  }
  *(f16x8*)(fh + (size_t)blk * DFC_ + c * 8) = vh;
  *(f16x8*)(fl + (size_t)blk * DFC_ + c * 8) = vl;
}

// ---------------------------------------------------------------------------
// K-tsplit: W[K][N] fp32 -> transposed f16 hi/lo planes Wt[N][K]
// ---------------------------------------------------------------------------
__global__ __launch_bounds__(256) void k_tsplit(const float* __restrict__ Wsrc,
                                                f16* __restrict__ Th,
                                                f16* __restrict__ Tl) {
  __shared__ float tile[32][33];
  const int bj = blockIdx.x, bi = blockIdx.y;
  const int tx = threadIdx.x & 31, ty = threadIdx.x >> 5;
  #pragma unroll
  for (int r = ty; r < 32; r += 8)
    tile[r][tx] = Wsrc[(size_t)(bi * 32 + r) * 1024 + bj * 32 + tx];
  __syncthreads();
  #pragma unroll
  for (int r = ty; r < 32; r += 8) {
    float v = tile[tx][r];
    f16 h = (f16)v;
    size_t o = (size_t)(bj * 32 + r) * 1024 + bi * 32 + tx;
    Th[o] = h;
    Tl[o] = (f16)(v - (float)h);
  }
}

// ---------------------------------------------------------------------------
// K3/K4: split-f16 3-product MFMA GEMM.
// out[m][n] = relu( sum_k (Ah+Al)[m][k] * (Wh+Wl)[k][n] + bias[n] )
//   via Ah@Wh + Ah@Wl + Al@Wh, fp32 accum.
// A: [MPAD][1024] f16 planes (row-major). B: Wt [1024][1024] f16 planes,
// already transposed so B-frags stage identically to A-frags.
// Tile 128x128, BK=32, 4 waves (2x2 of 64x64), 16x16x32_f16.
// ---------------------------------------------------------------------------
template <bool SPLIT_OUT>
__global__ __launch_bounds__(256) void k_gemm_f16x3(
    const f16* __restrict__ Ah, const f16* __restrict__ Al,
    const f16* __restrict__ Bh, const f16* __restrict__ Bl,
    const float* __restrict__ bias,
    f16* __restrict__ Oh, f16* __restrict__ Ol, float* __restrict__ Of,
    int M) {
  constexpr int K = DFC_;
  __shared__ f16 lds[16384];  // elems: Ah@0  Al@4096  Wh@8192  Wl@12288
  const int t = threadIdx.x;
  const int n0 = blockIdx.x * 128;
  const int r0 = blockIdx.y * 128;
  const int lane = t & 63, wave = t >> 6;
  const int quad = lane >> 4, lo = lane & 15;
  const int wm = wave >> 1, wn = wave & 1;

  // staging: thread t owns 16 bytes at linear offset t*16 within each 4 KB half
  const int srow = t >> 2;            // 0..63
  const int skb  = (t & 3) * 16;      // byte offset within 64B row-chunk
  const char* gA_h = (const char*)Ah + (size_t)(r0 + srow) * (K * 2) + skb;
  const char* gA_l = (const char*)Al + (size_t)(r0 + srow) * (K * 2) + skb;
  const char* gB_h = (const char*)Bh + (size_t)(n0 + srow) * (K * 2) + skb;
  const char* gB_l = (const char*)Bl + (size_t)(n0 + srow) * (K * 2) + skb;
  char* lb = (char*)lds + t * 16;
  const size_t rstride64 = (size_t)64 * K * 2;  // 64 rows in bytes

  f32x4 acc[4][4];
  #pragma unroll
  for (int mt = 0; mt < 4; mt++)
    #pragma unroll
    for (int nt = 0; nt < 4; nt++) acc[mt][nt] = (f32x4){0.f, 0.f, 0.f, 0.f};

  for (int kc = 0; kc < K / 32; kc++) {
    const size_t go = (size_t)kc * 64;   // 32 f16 = 64 B per row-chunk
    gload16(gA_h + go,             lb);
    gload16(gA_h + rstride64 + go, lb + 4096);
    gload16(gA_l + go,             lb + 8192);
    gload16(gA_l + rstride64 + go, lb + 12288);
    gload16(gB_h + go,             lb + 16384);
    gload16(gB_h + rstride64 + go, lb + 20480);
    gload16(gB_l + go,             lb + 24576);
    gload16(gB_l + rstride64 + go, lb + 28672);
    __syncthreads();

    f16x8 ah[4], al[4], bh[4], bl[4];
    #pragma unroll
    for (int mt = 0; mt < 4; mt++) {
      int row = wm * 64 + mt * 16 + lo;
      ah[mt] = *(const f16x8*)(lds + row * 32 + quad * 8);
      al[mt] = *(const f16x8*)(lds + 4096 + row * 32 + quad * 8);
    }
    #pragma unroll
    for (int nt = 0; nt < 4; nt++) {
      int row = wn * 64 + nt * 16 + lo;
      bh[nt] = *(const f16x8*)(lds + 8192 + row * 32 + quad * 8);
      bl[nt] = *(const f16x8*)(lds + 12288 + row * 32 + quad * 8);
    }
    #pragma unroll
    for (int mt = 0; mt < 4; mt++)
      #pragma unroll
      for (int nt = 0; nt < 4; nt++) {
        acc[mt][nt] = __builtin_amdgcn_mfma_f32_16x16x32_f16(ah[mt], bh[nt], acc[mt][nt], 0, 0, 0);
        acc[mt][nt] = __builtin_amdgcn_mfma_f32_16x16x32_f16(ah[mt], bl[nt], acc[mt][nt], 0, 0, 0);
        acc[mt][nt] = __builtin_amdgcn_mfma_f32_16x16x32_f16(al[mt], bh[nt], acc[mt][nt], 0, 0, 0);
      }
    __syncthreads();
  }

  // epilogue: C/D layout col=lane&15, row=quad*4+reg
  #pragma unroll
  for (int mt = 0; mt < 4; mt++)
    #pragma unroll
    for (int nt = 0; nt < 4; nt++) {
      int col = n0 + wn * 64 + nt * 16 + lo;
      float bv = bias[col];
      int rowb = r0 + wm * 64 + mt * 16 + quad * 4;
      #pragma unroll
      for (int r = 0; r < 4; r++) {
        int row = rowb + r;
        if (row < M) {
          float v = fmaxf(acc[mt][nt][r] + bv, 0.f);
          if (SPLIT_OUT) {
            f16 h = (f16)v;
            Oh[(size_t)row * DFC_ + col] = h;
            Ol[(size_t)row * DFC_ + col] = (f16)(v - (float)h);
          } else {
            Of[(size_t)row * DFC_ + col] = v;
          }
        }
      }
    }
}

// ---------------------------------------------------------------------------
// K5: logits = h2 @ w3 + b3, softmax, keep/argmax key.  One wave per row.
// ---------------------------------------------------------------------------
__global__ __launch_bounds__(256) void k_head(const float* __restrict__ h2,
                                              const float* __restrict__ w3,
                                              const float* __restrict__ b3,
                                              float* __restrict__ s_out,
                                              int* __restrict__ key_out) {
  const int wave = threadIdx.x >> 6;
  const int lane = threadIdx.x & 63;
  const int row = blockIdx.x * 4 + wave;
  if (row >= M_) return;
  const float* hr = h2 + (size_t)row * DFC_;
  float a0 = 0.f, a1 = 0.f, a2 = 0.f, a3 = 0.f;
  for (int k = lane; k < DFC_; k += 64) {
    float hv = hr[k];
    float4 wv = *(const float4*)(w3 + k * 4);
    a0 = fmaf(hv, wv.x, a0);
    a1 = fmaf(hv, wv.y, a1);
    a2 = fmaf(hv, wv.z, a2);
    a3 = fmaf(hv, wv.w, a3);
  }
  #pragma unroll
  for (int off = 32; off >= 1; off >>= 1) {
    a0 += __shfl_down(a0, off);
    a1 += __shfl_down(a1, off);
    a2 += __shfl_down(a2, off);
    a3 += __shfl_down(a3, off);
  }
  if (lane == 0) {
    float l0 = a0 + b3[0], l1 = a1 + b3[1], l2 = a2 + b3[2], l3 = a3 + b3[3];
    float mx = fmaxf(fmaxf(l0, l1), fmaxf(l2, l3));
    float e0 = expf(l0 - mx), e1 = expf(l1 - mx), e2 = expf(l2 - mx), e3 = expf(l3 - mx);
    float inv = 1.f / (e0 + e1 + e2 + e3);
    float s0 = e0 * inv, s1 = e1 * inv, s2 = e2 * inv, s3 = e3 * inv;
    *(float4*)(s_out + (size_t)row * 4) = make_float4(s0, s1, s2, s3);
    bool keep = ((s1 > 0.25f) || (s2 > 0.25f) || (s3 > 0.25f)) && (s0 < 0.25f);
    int am = 0; float best = s0;
    if (s1 > best) { best = s1; am = 1; }
    if (s2 > best) { best = s2; am = 2; }
    if (s3 > best) { best = s3; am = 3; }
    key_out[row] = keep ? am : -1;
  }
}

// ---------------------------------------------------------------------------
// K6: per-batch stable counting sort (5 classes) + cyclic select.
// ---------------------------------------------------------------------------
__global__ __launch_bounds__(1024) void k_select(const int* __restrict__ key,
                                                 const float* __restrict__ lines,
                                                 const float* __restrict__ s,
                                                 float* __restrict__ out_lines,
                                                 float* __restrict__ out_score) {
  __shared__ int s_ord[L_];
  __shared__ int s_scan[1024];
  __shared__ int s_tot[5];
  const int b = blockIdx.x;
  const int t = threadIdx.x;
  const int base_l = t * 5;
  int cls[5];
  int c[5] = {0, 0, 0, 0, 0};
  #pragma unroll
  for (int i = 0; i < 5; i++) {
    int l = base_l + i;
    int cl = -1;
    if (l < L_) {
      int k = key[b * L_ + l];
      cl = (k < 0) ? 4 : (3 - k);
      c[cl]++;
    }
    cls[i] = cl;
  }
  int pf[5];
  for (int cc = 0; cc < 5; cc++) {
    s_scan[t] = c[cc];
    __syncthreads();
    for (int off = 1; off < 1024; off <<= 1) {
      int add = (t >= off) ? s_scan[t - off] : 0;
      __syncthreads();
      s_scan[t] += add;
      __syncthreads();
    }
    pf[cc] = s_scan[t] - c[cc];
    if (t == 1023) s_tot[cc] = s_scan[1023];
    __syncthreads();
  }
  int basec[5];
  basec[0] = 0;
  #pragma unroll
  for (int cc = 1; cc < 5; cc++) basec[cc] = basec[cc - 1] + s_tot[cc - 1];
  int run[5] = {0, 0, 0, 0, 0};
  #pragma unroll
  for (int i = 0; i < 5; i++) {
    if (cls[i] >= 0) {
      int cl = cls[i];
      int pos = basec[cl] + pf[cl] + run[cl];
      run[cl]++;
      s_ord[pos] = base_l + i;
    }
  }
  const int cnt = L_ - s_tot[4];
  __syncthreads();
  for (int j = t; j < NOUT_; j += 1024) {
    float4 lv = make_float4(0.f, 0.f, 0.f, 0.f);
    float4 sv = make_float4(0.f, 0.f, 0.f, 0.f);
    if (cnt > 0) {
      int idx = s_ord[j % cnt];
      lv = *(const float4*)(lines + (size_t)(b * L_ + idx) * 4);
      sv = *(const float4*)(s + (size_t)(b * L_ + idx) * 4);
    }
    *(float4*)(out_lines + (size_t)(b * NOUT_ + j) * 4) = lv;
    *(float4*)(out_score + (size_t)(b * NOUT_ + j) * 4) = sv;
  }
}

// ---------------------------------------------------------------------------
extern "C" void kernel_launch(void* const* d_in, const int* in_sizes, int n_in,
                              void* d_out, int out_size, void* d_ws, size_t ws_size,
                              hipStream_t stream) {
  const float* feature = (const float*)d_in[0];
  const float* lines   = (const float*)d_in[1];
  const float* fc1_w   = (const float*)d_in[2];
  const float* fc1_b   = (const float*)d_in[3];
  const float* w1      = (const float*)d_in[4];
  const float* b1      = (const float*)d_in[5];
  const float* w2      = (const float*)d_in[6];
  const float* b2      = (const float*)d_in[7];
  const float* w3      = (const float*)d_in[8];
  const float* b3      = (const float*)d_in[9];

  float* out_lines = (float*)d_out;
  float* out_score = out_lines + B_ * NOUT_ * 4;
  float* s_out     = out_score + B_ * NOUT_ * 4;

  // workspace layout (bytes):
  //   region X : [0, 134217728)        conv out x (fp32, channel-last);
  //              after k_sample x is dead -> h1h @0, h1l @41156608 (alias)
  //   fh       : [134217728, +41156608)   feat hi  (MPAD x 1024 f16)
  //   fl       : [175374336, +41156608)   feat lo
  //              after GEMM1 feat is dead -> h2 fp32 (81920000 B) aliases fh
  //   wt       : [216530944, +4*2097152)  wt1h wt1l wt2h wt2l
  //   keys     : [224919552, +80000)
  char* ws = (char*)d_ws;
  float* x    = (float*)(ws);
  f16*   h1h  = (f16*)(ws);
  f16*   h1l  = (f16*)(ws + 41156608ull);
  f16*   fh   = (f16*)(ws + 134217728ull);
  f16*   fl   = (f16*)(ws + 134217728ull + 41156608ull);
  float* h2   = (float*)(ws + 134217728ull);
  f16*   wt1h = (f16*)(ws + 216530944ull);
  f16*   wt1l = (f16*)(ws + 216530944ull + 2097152ull);
  f16*   wt2h = (f16*)(ws + 216530944ull + 2ull * 2097152ull);
  f16*   wt2l = (f16*)(ws + 216530944ull + 3ull * 2097152ull);
  int*   keys = (int*)(ws + 224919552ull);

  k_tsplit<<<dim3(32, 32), 256, 0, stream>>>(w1, wt1h, wt1l);
  k_tsplit<<<dim3(32, 32), 256, 0, stream>>>(w2, wt2h, wt2l);
  k_conv<<<dim3(HW_ / 64, B_), 256, 0, stream>>>(feature, fc1_w, fc1_b, x);
  k_sample<<<dim3(M_), 128, 0, stream>>>(x, lines, fh, fl);
  k_gemm_f16x3<true><<<dim3(8, MPAD_ / 128), 256, 0, stream>>>(
      fh, fl, wt1h, wt1l, b1, h1h, h1l, nullptr, M_);
  k_gemm_f16x3<false><<<dim3(8, MPAD_ / 128), 256, 0, stream>>>(
      h1h, h1l, wt2h, wt2l, b2, nullptr, nullptr, h2, M_);
  k_head<<<dim3(M_ / 4), 256, 0, stream>>>(h2, w3, b3, s_out, keys);
  k_select<<<dim3(B_), 1024, 0, stream>>>(keys, lines, s_out, out_lines, out_score);
}

// Round 3
// 953.871 us; speedup vs baseline: 1.8845x; 1.1777x over previous
//
#include <hip/hip_runtime.h>
#include <cstdint>
#include <cstddef>

#define B_     4
#define L_     5000
#define H_     256
#define W_     256
#define HW_    65536
#define CIN_   256
#define DLOI_  128
#define NPTS0_ 32
#define NPTS1_ 8
#define DFC_   1024
#define NOUT_  2500
#define M_     (B_*L_)   // 20000
#define MPAD_  20096     // 157 * 128

typedef _Float16 f16;
typedef _Float16 f16x4 __attribute__((ext_vector_type(4)));
typedef _Float16 f16x8 __attribute__((ext_vector_type(8)));
typedef float    f32x4 __attribute__((ext_vector_type(4)));

__device__ __forceinline__ void gload16(const void* g, void* l) {
  __builtin_amdgcn_global_load_lds(
      (const __attribute__((address_space(1))) void*)g,
      (__attribute__((address_space(3))) void*)l, 16, 0, 0);
}

// ---------------------------------------------------------------------------
// K0a: split fc1_w [128][256] fp32 -> f16 hi/lo planes (same [n][k] layout)
// ---------------------------------------------------------------------------
__global__ __launch_bounds__(256) void k_wsplit(const float* __restrict__ src,
                                                f16* __restrict__ h,
                                                f16* __restrict__ l) {
  int i = (blockIdx.x * 256 + threadIdx.x) * 4;
  float4 v = *(const float4*)(src + i);
  f16 h0 = (f16)v.x, h1 = (f16)v.y, h2 = (f16)v.z, h3 = (f16)v.w;
  *(f16x4*)(h + i) = (f16x4){h0, h1, h2, h3};
  *(f16x4*)(l + i) = (f16x4){(f16)(v.x - (float)h0), (f16)(v.y - (float)h1),
                             (f16)(v.z - (float)h2), (f16)(v.w - (float)h3)};
}

// ---------------------------------------------------------------------------
// K1: conv as split-f16 MFMA GEMM.  M=262144 pixels, N=128, K=256.
// A[m=p][k=c] = feature[b][c][p] (transpose+split fused into LDS staging).
// B[n=o][k=c] = fc1_w h/l planes, staged via global_load_lds.
// Tile 128m x 128n, BK=32, 4 waves (2x2 of 64x64), 16x16x32_f16, 3 products.
// ---------------------------------------------------------------------------
__global__ __launch_bounds__(256) void k_conv_mfma(const float* __restrict__ fin,
                                                   const f16* __restrict__ wh,
                                                   const f16* __restrict__ wl,
                                                   const float* __restrict__ bias,
                                                   float* __restrict__ xout) {
  __shared__ f16 lds[16384];  // elems: Ah@0  Al@4096  Bh@8192  Bl@12288
  const int t = threadIdx.x;
  const int P0 = blockIdx.x * 128;        // global pixel row base
  const int b  = P0 >> 16;
  const int ph0 = P0 & 65535;
  const int lane = t & 63, wave = t >> 6;
  const int quad = lane >> 4, lo = lane & 15;
  const int wm = wave >> 1, wn = wave & 1;

  // A staging: thread handles 4 channels x 4 pixels
  const int c_base = (t & 7) * 4;         // 0..28
  const int p = (t >> 3) * 4;             // 0..124
  const size_t fbase = (size_t)b * CIN_ * HW_ + (size_t)ph0 + p;

  // B staging: [row n][32 k] chunks, 64 B per row-chunk
  const int srow = t >> 2;                // 0..63
  const int skb  = (t & 3) * 16;
  const char* gBh = (const char*)wh + (size_t)srow * 512 + skb;
  const char* gBl = (const char*)wl + (size_t)srow * 512 + skb;
  char* ldsB = (char*)lds + t * 16;

  f32x4 acc[4][4];
  #pragma unroll
  for (int mt = 0; mt < 4; mt++)
    #pragma unroll
    for (int nt = 0; nt < 4; nt++) acc[mt][nt] = (f32x4){0.f, 0.f, 0.f, 0.f};

  float4 av[4], nv[4];
  #pragma unroll
  for (int j = 0; j < 4; j++)
    av[j] = *(const float4*)(fin + fbase + (size_t)(c_base + j) * HW_);

  for (int kc = 0; kc < 8; kc++) {
    // --- B: direct global->LDS (drained by the barrier) ---
    const size_t bko = (size_t)kc * 64;
    gload16(gBh + bko,         ldsB + 16384);          // rows 0..63
    gload16(gBh + 32768 + bko, ldsB + 16384 + 4096);   // rows 64..127
    gload16(gBl + bko,         ldsB + 24576);
    gload16(gBl + 32768 + bko, ldsB + 24576 + 4096);

    // --- A: convert + transposed LDS write (Ah[p][c], Al[p][c]) ---
    #pragma unroll
    for (int i = 0; i < 4; i++) {
      f16 hh[4], ll[4];
      #pragma unroll
      for (int j = 0; j < 4; j++) {
        float v = ((const float*)&av[j])[i];
        hh[j] = (f16)v;
        ll[j] = (f16)(v - (float)hh[j]);
      }
      *(f16x4*)(&lds[(p + i) * 32 + c_base])        = (f16x4){hh[0], hh[1], hh[2], hh[3]};
      *(f16x4*)(&lds[4096 + (p + i) * 32 + c_base]) = (f16x4){ll[0], ll[1], ll[2], ll[3]};
    }
    __syncthreads();

    // --- prefetch next fp32 A chunk during MFMA section ---
    if (kc < 7) {
      #pragma unroll
      for (int j = 0; j < 4; j++)
        nv[j] = *(const float4*)(fin + fbase + (size_t)((kc + 1) * 32 + c_base + j) * HW_);
    }

    f16x8 ah[4], al[4], bh4[4], bl4[4];
    #pragma unroll
    for (int mt = 0; mt < 4; mt++) {
      int row = wm * 64 + mt * 16 + lo;
      ah[mt] = *(const f16x8*)(&lds[row * 32 + quad * 8]);
      al[mt] = *(const f16x8*)(&lds[4096 + row * 32 + quad * 8]);
    }
    #pragma unroll
    for (int nt = 0; nt < 4; nt++) {
      int row = wn * 64 + nt * 16 + lo;
      bh4[nt] = *(const f16x8*)(&lds[8192 + row * 32 + quad * 8]);
      bl4[nt] = *(const f16x8*)(&lds[12288 + row * 32 + quad * 8]);
    }
    #pragma unroll
    for (int mt = 0; mt < 4; mt++)
      #pragma unroll
      for (int nt = 0; nt < 4; nt++) {
        acc[mt][nt] = __builtin_amdgcn_mfma_f32_16x16x32_f16(ah[mt], bh4[nt], acc[mt][nt], 0, 0, 0);
        acc[mt][nt] = __builtin_amdgcn_mfma_f32_16x16x32_f16(ah[mt], bl4[nt], acc[mt][nt], 0, 0, 0);
        acc[mt][nt] = __builtin_amdgcn_mfma_f32_16x16x32_f16(al[mt], bh4[nt], acc[mt][nt], 0, 0, 0);
      }
    __syncthreads();
    #pragma unroll
    for (int j = 0; j < 4; j++) av[j] = nv[j];
  }

  // epilogue: C/D layout col=lane&15, row=quad*4+reg;  x[P][o] fp32, +bias
  #pragma unroll
  for (int nt = 0; nt < 4; nt++) {
    int col = wn * 64 + nt * 16 + lo;
    float bv = bias[col];
    #pragma unroll
    for (int mt = 0; mt < 4; mt++) {
      int rowb = P0 + wm * 64 + mt * 16 + quad * 4;
      #pragma unroll
      for (int r = 0; r < 4; r++)
        xout[(size_t)(rowb + r) * DLOI_ + col] = acc[mt][nt][r] + bv;
    }
  }
}

// ---------------------------------------------------------------------------
// K2: sample 32 pts/line, bilinear, maxpool by 4 -> feat as f16 hi/lo planes
// ---------------------------------------------------------------------------
__global__ __launch_bounds__(128) void k_sample(const float* __restrict__ x,
                                                const float* __restrict__ lines,
                                                f16* __restrict__ fh,
                                                f16* __restrict__ fl) {
  const int blk = blockIdx.x;   // b*L + l
  const int b = blk / L_;
  const int c = threadIdx.x;
  const float* ln = lines + (size_t)blk * 4;
  const float e0x = ln[0], e0y = ln[1], e1x = ln[2], e1y = ln[3];
  const float* xb = x + (size_t)b * HW_ * DLOI_;
  f16x8 vh, vl;
  for (int q = 0; q < NPTS1_; q++) {
    float m = -1e30f;
    #pragma unroll
    for (int r = 0; r < 4; r++) {
      int i = q * 4 + r;
      float lam = (float)i * (1.0f / 31.0f);
      float px = e0x * lam + e1x * (1.f - lam) - 0.5f;
      float py = e0y * lam + e1y * (1.f - lam) - 0.5f;
      float px0 = fminf(fmaxf(floorf(px), 0.f), 255.f);
      float py0 = fminf(fmaxf(floorf(py), 0.f), 255.f);
      float px1 = fminf(px0 + 1.f, 255.f);
      float py1 = fminf(py0 + 1.f, 255.f);
      int ix0 = (int)px0, iy0 = (int)py0, ix1 = (int)px1, iy1 = (int)py1;
      float w00 = (px1 - px) * (py1 - py);
      float w10 = (px - px0) * (py1 - py);
      float w01 = (px1 - px) * (py - py0);
      float w11 = (px - px0) * (py - py0);
      float v = w00 * xb[(size_t)(ix0 * W_ + iy0) * DLOI_ + c]
              + w10 * xb[(size_t)(ix1 * W_ + iy0) * DLOI_ + c]
              + w01 * xb[(size_t)(ix0 * W_ + iy1) * DLOI_ + c]
              + w11 * xb[(size_t)(ix1 * W_ + iy1) * DLOI_ + c];
      m = fmaxf(m, v);
    }
    f16 h = (f16)m;
    vh[q] = h;
    vl[q] = (f16)(m - (float)h);
  }
  *(f16x8*)(fh + (size_t)blk * DFC_ + c * 8) = vh;
  *(f16x8*)(fl + (size_t)blk * DFC_ + c * 8) = vl;
}

// ---------------------------------------------------------------------------
// K-tsplit: W[K][N] fp32 -> transposed f16 hi/lo planes Wt[N][K]
// ---------------------------------------------------------------------------
__global__ __launch_bounds__(256) void k_tsplit(const float* __restrict__ Wsrc,
                                                f16* __restrict__ Th,
                                                f16* __restrict__ Tl) {
  __shared__ float tile[32][33];
  const int bj = blockIdx.x, bi = blockIdx.y;
  const int tx = threadIdx.x & 31, ty = threadIdx.x >> 5;
  #pragma unroll
  for (int r = ty; r < 32; r += 8)
    tile[r][tx] = Wsrc[(size_t)(bi * 32 + r) * 1024 + bj * 32 + tx];
  __syncthreads();
  #pragma unroll
  for (int r = ty; r < 32; r += 8) {
    float v = tile[tx][r];
    f16 h = (f16)v;
    size_t o = (size_t)(bj * 32 + r) * 1024 + bi * 32 + tx;
    Th[o] = h;
    Tl[o] = (f16)(v - (float)h);
  }
}

// ---------------------------------------------------------------------------
// K3/K4: split-f16 3-product MFMA GEMM (MLP layers)
// ---------------------------------------------------------------------------
template <bool SPLIT_OUT>
__global__ __launch_bounds__(256) void k_gemm_f16x3(
    const f16* __restrict__ Ah, const f16* __restrict__ Al,
    const f16* __restrict__ Bh, const f16* __restrict__ Bl,
    const float* __restrict__ bias,
    f16* __restrict__ Oh, f16* __restrict__ Ol, float* __restrict__ Of,
    int M) {
  constexpr int K = DFC_;
  __shared__ f16 lds[16384];
  const int t = threadIdx.x;
  const int n0 = blockIdx.x * 128;
  const int r0 = blockIdx.y * 128;
  const int lane = t & 63, wave = t >> 6;
  const int quad = lane >> 4, lo = lane & 15;
  const int wm = wave >> 1, wn = wave & 1;

  const int srow = t >> 2;
  const int skb  = (t & 3) * 16;
  const char* gA_h = (const char*)Ah + (size_t)(r0 + srow) * (K * 2) + skb;
  const char* gA_l = (const char*)Al + (size_t)(r0 + srow) * (K * 2) + skb;
  const char* gB_h = (const char*)Bh + (size_t)(n0 + srow) * (K * 2) + skb;
  const char* gB_l = (const char*)Bl + (size_t)(n0 + srow) * (K * 2) + skb;
  char* lb = (char*)lds + t * 16;
  const size_t rstride64 = (size_t)64 * K * 2;

  f32x4 acc[4][4];
  #pragma unroll
  for (int mt = 0; mt < 4; mt++)
    #pragma unroll
    for (int nt = 0; nt < 4; nt++) acc[mt][nt] = (f32x4){0.f, 0.f, 0.f, 0.f};

  for (int kc = 0; kc < K / 32; kc++) {
    const size_t go = (size_t)kc * 64;
    gload16(gA_h + go,             lb);
    gload16(gA_h + rstride64 + go, lb + 4096);
    gload16(gA_l + go,             lb + 8192);
    gload16(gA_l + rstride64 + go, lb + 12288);
    gload16(gB_h + go,             lb + 16384);
    gload16(gB_h + rstride64 + go, lb + 20480);
    gload16(gB_l + go,             lb + 24576);
    gload16(gB_l + rstride64 + go, lb + 28672);
    __syncthreads();

    f16x8 ah[4], al[4], bh[4], bl[4];
    #pragma unroll
    for (int mt = 0; mt < 4; mt++) {
      int row = wm * 64 + mt * 16 + lo;
      ah[mt] = *(const f16x8*)(lds + row * 32 + quad * 8);
      al[mt] = *(const f16x8*)(lds + 4096 + row * 32 + quad * 8);
    }
    #pragma unroll
    for (int nt = 0; nt < 4; nt++) {
      int row = wn * 64 + nt * 16 + lo;
      bh[nt] = *(const f16x8*)(lds + 8192 + row * 32 + quad * 8);
      bl[nt] = *(const f16x8*)(lds + 12288 + row * 32 + quad * 8);
    }
    #pragma unroll
    for (int mt = 0; mt < 4; mt++)
      #pragma unroll
      for (int nt = 0; nt < 4; nt++) {
        acc[mt][nt] = __builtin_amdgcn_mfma_f32_16x16x32_f16(ah[mt], bh[nt], acc[mt][nt], 0, 0, 0);
        acc[mt][nt] = __builtin_amdgcn_mfma_f32_16x16x32_f16(ah[mt], bl[nt], acc[mt][nt], 0, 0, 0);
        acc[mt][nt] = __builtin_amdgcn_mfma_f32_16x16x32_f16(al[mt], bh[nt], acc[mt][nt], 0, 0, 0);
      }
    __syncthreads();
  }

  #pragma unroll
  for (int mt = 0; mt < 4; mt++)
    #pragma unroll
    for (int nt = 0; nt < 4; nt++) {
      int col = n0 + wn * 64 + nt * 16 + lo;
      float bv = bias[col];
      int rowb = r0 + wm * 64 + mt * 16 + quad * 4;
      #pragma unroll
      for (int r = 0; r < 4; r++) {
        int row = rowb + r;
        if (row < M) {
          float v = fmaxf(acc[mt][nt][r] + bv, 0.f);
          if (SPLIT_OUT) {
            f16 h = (f16)v;
            Oh[(size_t)row * DFC_ + col] = h;
            Ol[(size_t)row * DFC_ + col] = (f16)(v - (float)h);
          } else {
            Of[(size_t)row * DFC_ + col] = v;
          }
        }
      }
    }
}

// ---------------------------------------------------------------------------
// K5: logits = h2 @ w3 + b3, softmax, keep/argmax key.  One wave per row.
// ---------------------------------------------------------------------------
__global__ __launch_bounds__(256) void k_head(const float* __restrict__ h2,
                                              const float* __restrict__ w3,
                                              const float* __restrict__ b3,
                                              float* __restrict__ s_out,
                                              int* __restrict__ key_out) {
  const int wave = threadIdx.x >> 6;
  const int lane = threadIdx.x & 63;
  const int row = blockIdx.x * 4 + wave;
  if (row >= M_) return;
  const float* hr = h2 + (size_t)row * DFC_;
  float a0 = 0.f, a1 = 0.f, a2 = 0.f, a3 = 0.f;
  for (int k = lane; k < DFC_; k += 64) {
    float hv = hr[k];
    float4 wv = *(const float4*)(w3 + k * 4);
    a0 = fmaf(hv, wv.x, a0);
    a1 = fmaf(hv, wv.y, a1);
    a2 = fmaf(hv, wv.z, a2);
    a3 = fmaf(hv, wv.w, a3);
  }
  #pragma unroll
  for (int off = 32; off >= 1; off >>= 1) {
    a0 += __shfl_down(a0, off);
    a1 += __shfl_down(a1, off);
    a2 += __shfl_down(a2, off);
    a3 += __shfl_down(a3, off);
  }
  if (lane == 0) {
    float l0 = a0 + b3[0], l1 = a1 + b3[1], l2 = a2 + b3[2], l3 = a3 + b3[3];
    float mx = fmaxf(fmaxf(l0, l1), fmaxf(l2, l3));
    float e0 = expf(l0 - mx), e1 = expf(l1 - mx), e2 = expf(l2 - mx), e3 = expf(l3 - mx);
    float inv = 1.f / (e0 + e1 + e2 + e3);
    float s0 = e0 * inv, s1 = e1 * inv, s2 = e2 * inv, s3 = e3 * inv;
    *(float4*)(s_out + (size_t)row * 4) = make_float4(s0, s1, s2, s3);
    bool keep = ((s1 > 0.25f) || (s2 > 0.25f) || (s3 > 0.25f)) && (s0 < 0.25f);
    int am = 0; float best = s0;
    if (s1 > best) { best = s1; am = 1; }
    if (s2 > best) { best = s2; am = 2; }
    if (s3 > best) { best = s3; am = 3; }
    key_out[row] = keep ? am : -1;
  }
}

// ---------------------------------------------------------------------------
// K6: per-batch stable counting sort (5 classes) + cyclic select.
// ---------------------------------------------------------------------------
__global__ __launch_bounds__(1024) void k_select(const int* __restrict__ key,
                                                 const float* __restrict__ lines,
                                                 const float* __restrict__ s,
                                                 float* __restrict__ out_lines,
                                                 float* __restrict__ out_score) {
  __shared__ int s_ord[L_];
  __shared__ int s_scan[1024];
  __shared__ int s_tot[5];
  const int b = blockIdx.x;
  const int t = threadIdx.x;
  const int base_l = t * 5;
  int cls[5];
  int c[5] = {0, 0, 0, 0, 0};
  #pragma unroll
  for (int i = 0; i < 5; i++) {
    int l = base_l + i;
    int cl = -1;
    if (l < L_) {
      int k = key[b * L_ + l];
      cl = (k < 0) ? 4 : (3 - k);
      c[cl]++;
    }
    cls[i] = cl;
  }
  int pf[5];
  for (int cc = 0; cc < 5; cc++) {
    s_scan[t] = c[cc];
    __syncthreads();
    for (int off = 1; off < 1024; off <<= 1) {
      int add = (t >= off) ? s_scan[t - off] : 0;
      __syncthreads();
      s_scan[t] += add;
      __syncthreads();
    }
    pf[cc] = s_scan[t] - c[cc];
    if (t == 1023) s_tot[cc] = s_scan[1023];
    __syncthreads();
  }
  int basec[5];
  basec[0] = 0;
  #pragma unroll
  for (int cc = 1; cc < 5; cc++) basec[cc] = basec[cc - 1] + s_tot[cc - 1];
  int run[5] = {0, 0, 0, 0, 0};
  #pragma unroll
  for (int i = 0; i < 5; i++) {
    if (cls[i] >= 0) {
      int cl = cls[i];
      int pos = basec[cl] + pf[cl] + run[cl];
      run[cl]++;
      s_ord[pos] = base_l + i;
    }
  }
  const int cnt = L_ - s_tot[4];
  __syncthreads();
  for (int j = t; j < NOUT_; j += 1024) {
    float4 lv = make_float4(0.f, 0.f, 0.f, 0.f);
    float4 sv = make_float4(0.f, 0.f, 0.f, 0.f);
    if (cnt > 0) {
      int idx = s_ord[j % cnt];
      lv = *(const float4*)(lines + (size_t)(b * L_ + idx) * 4);
      sv = *(const float4*)(s + (size_t)(b * L_ + idx) * 4);
    }
    *(float4*)(out_lines + (size_t)(b * NOUT_ + j) * 4) = lv;
    *(float4*)(out_score + (size_t)(b * NOUT_ + j) * 4) = sv;
  }
}

// ---------------------------------------------------------------------------
extern "C" void kernel_launch(void* const* d_in, const int* in_sizes, int n_in,
                              void* d_out, int out_size, void* d_ws, size_t ws_size,
                              hipStream_t stream) {
  const float* feature = (const float*)d_in[0];
  const float* lines   = (const float*)d_in[1];
  const float* fc1_w   = (const float*)d_in[2];
  const float* fc1_b   = (const float*)d_in[3];
  const float* w1      = (const float*)d_in[4];
  const float* b1      = (const float*)d_in[5];
  const float* w2      = (const float*)d_in[6];
  const float* b2      = (const float*)d_in[7];
  const float* w3      = (const float*)d_in[8];
  const float* b3      = (const float*)d_in[9];

  float* out_lines = (float*)d_out;
  float* out_score = out_lines + B_ * NOUT_ * 4;
  float* s_out     = out_score + B_ * NOUT_ * 4;

  // workspace layout (bytes):
  //   region X : [0, 134217728)         conv out x (fp32, channel-last);
  //              after k_sample -> h1h @0, h1l @41156608 (alias)
  //   fh       : [134217728, +41156608) feat hi  (MPAD x 1024 f16)
  //   fl       : [175374336, +41156608) feat lo
  //              after GEMM1 -> h2 fp32 (81920000 B) aliases fh
  //   wt       : [216530944, +4*2097152)  wt1h wt1l wt2h wt2l
  //   keys     : [224919552, +80000)
  //   wc       : [224999552, +2*65536)  fc1_w f16 hi/lo planes
  char* ws = (char*)d_ws;
  float* x    = (float*)(ws);
  f16*   h1h  = (f16*)(ws);
  f16*   h1l  = (f16*)(ws + 41156608ull);
  f16*   fh   = (f16*)(ws + 134217728ull);
  f16*   fl   = (f16*)(ws + 134217728ull + 41156608ull);
  float* h2   = (float*)(ws + 134217728ull);
  f16*   wt1h = (f16*)(ws + 216530944ull);
  f16*   wt1l = (f16*)(ws + 216530944ull + 2097152ull);
  f16*   wt2h = (f16*)(ws + 216530944ull + 2ull * 2097152ull);
  f16*   wt2l = (f16*)(ws + 216530944ull + 3ull * 2097152ull);
  int*   keys = (int*)(ws + 224919552ull);
  f16*   wc_h = (f16*)(ws + 224999552ull);
  f16*   wc_l = (f16*)(ws + 224999552ull + 65536ull);

  k_wsplit<<<dim3(32), 256, 0, stream>>>(fc1_w, wc_h, wc_l);
  k_tsplit<<<dim3(32, 32), 256, 0, stream>>>(w1, wt1h, wt1l);
  k_tsplit<<<dim3(32, 32), 256, 0, stream>>>(w2, wt2h, wt2l);
  k_conv_mfma<<<dim3((B_ * HW_) / 128), 256, 0, stream>>>(feature, wc_h, wc_l, fc1_b, x);
  k_sample<<<dim3(M_), 128, 0, stream>>>(x, lines, fh, fl);
  k_gemm_f16x3<true><<<dim3(8, MPAD_ / 128), 256, 0, stream>>>(
      fh, fl, wt1h, wt1l, b1, h1h, h1l, nullptr, M_);
  k_gemm_f16x3<false><<<dim3(8, MPAD_ / 128), 256, 0, stream>>>(
      h1h, h1l, wt2h, wt2l, b2, nullptr, nullptr, h2, M_);
  k_head<<<dim3(M_ / 4), 256, 0, stream>>>(h2, w3, b3, s_out, keys);
  k_select<<<dim3(B_), 1024, 0, stream>>>(keys, lines, s_out, out_lines, out_score);
}

// Round 4
// 888.291 us; speedup vs baseline: 2.0237x; 1.0738x over previous
//
#include <hip/hip_runtime.h>
#include <cstdint>
#include <cstddef>

#define B_     4
#define L_     5000
#define H_     256
#define W_     256
#define HW_    65536
#define CIN_   256
#define DLOI_  128
#define NPTS0_ 32
#define NPTS1_ 8
#define DFC_   1024
#define NOUT_  2500
#define M_     (B_*L_)   // 20000
#define MPAD_  20096     // 157 * 128
#define NBAND_ 157       // MPAD_/128

typedef _Float16 f16;
typedef _Float16 f16x4 __attribute__((ext_vector_type(4)));
typedef _Float16 f16x8 __attribute__((ext_vector_type(8)));
typedef float    f32x4 __attribute__((ext_vector_type(4)));

__device__ __forceinline__ void gload16(const void* g, void* l) {
  __builtin_amdgcn_global_load_lds(
      (const __attribute__((address_space(1))) void*)g,
      (__attribute__((address_space(3))) void*)l, 16, 0, 0);
}

// ---------------------------------------------------------------------------
// K0a: split fc1_w [128][256] fp32 -> f16 hi/lo planes (same [n][k] layout)
// ---------------------------------------------------------------------------
__global__ __launch_bounds__(256) void k_wsplit(const float* __restrict__ src,
                                                f16* __restrict__ h,
                                                f16* __restrict__ l) {
  int i = (blockIdx.x * 256 + threadIdx.x) * 4;
  float4 v = *(const float4*)(src + i);
  f16 h0 = (f16)v.x, h1 = (f16)v.y, h2 = (f16)v.z, h3 = (f16)v.w;
  *(f16x4*)(h + i) = (f16x4){h0, h1, h2, h3};
  *(f16x4*)(l + i) = (f16x4){(f16)(v.x - (float)h0), (f16)(v.y - (float)h1),
                             (f16)(v.z - (float)h2), (f16)(v.w - (float)h3)};
}

// ---------------------------------------------------------------------------
// K1: conv as split-f16 MFMA GEMM.  M=262144 pixels, N=128, K=256.
// ---------------------------------------------------------------------------
__global__ __launch_bounds__(256) void k_conv_mfma(const float* __restrict__ fin,
                                                   const f16* __restrict__ wh,
                                                   const f16* __restrict__ wl,
                                                   const float* __restrict__ bias,
                                                   float* __restrict__ xout) {
  __shared__ f16 lds[16384];  // elems: Ah@0  Al@4096  Bh@8192  Bl@12288
  const int t = threadIdx.x;
  const int P0 = blockIdx.x * 128;
  const int b  = P0 >> 16;
  const int ph0 = P0 & 65535;
  const int lane = t & 63, wave = t >> 6;
  const int quad = lane >> 4, lo = lane & 15;
  const int wm = wave >> 1, wn = wave & 1;

  const int c_base = (t & 7) * 4;
  const int p = (t >> 3) * 4;
  const size_t fbase = (size_t)b * CIN_ * HW_ + (size_t)ph0 + p;

  const int srow = t >> 2;
  const int skb  = (t & 3) * 16;
  const char* gBh = (const char*)wh + (size_t)srow * 512 + skb;
  const char* gBl = (const char*)wl + (size_t)srow * 512 + skb;
  char* ldsB = (char*)lds + t * 16;

  f32x4 acc[4][4];
  #pragma unroll
  for (int mt = 0; mt < 4; mt++)
    #pragma unroll
    for (int nt = 0; nt < 4; nt++) acc[mt][nt] = (f32x4){0.f, 0.f, 0.f, 0.f};

  float4 av[4], nv[4];
  #pragma unroll
  for (int j = 0; j < 4; j++)
    av[j] = *(const float4*)(fin + fbase + (size_t)(c_base + j) * HW_);

  for (int kc = 0; kc < 8; kc++) {
    const size_t bko = (size_t)kc * 64;
    gload16(gBh + bko,         ldsB + 16384);
    gload16(gBh + 32768 + bko, ldsB + 16384 + 4096);
    gload16(gBl + bko,         ldsB + 24576);
    gload16(gBl + 32768 + bko, ldsB + 24576 + 4096);

    #pragma unroll
    for (int i = 0; i < 4; i++) {
      f16 hh[4], ll[4];
      #pragma unroll
      for (int j = 0; j < 4; j++) {
        float v = ((const float*)&av[j])[i];
        hh[j] = (f16)v;
        ll[j] = (f16)(v - (float)hh[j]);
      }
      *(f16x4*)(&lds[(p + i) * 32 + c_base])        = (f16x4){hh[0], hh[1], hh[2], hh[3]};
      *(f16x4*)(&lds[4096 + (p + i) * 32 + c_base]) = (f16x4){ll[0], ll[1], ll[2], ll[3]};
    }
    __syncthreads();

    if (kc < 7) {
      #pragma unroll
      for (int j = 0; j < 4; j++)
        nv[j] = *(const float4*)(fin + fbase + (size_t)((kc + 1) * 32 + c_base + j) * HW_);
    }

    f16x8 ah[4], al[4], bh4[4], bl4[4];
    #pragma unroll
    for (int mt = 0; mt < 4; mt++) {
      int row = wm * 64 + mt * 16 + lo;
      ah[mt] = *(const f16x8*)(&lds[row * 32 + quad * 8]);
      al[mt] = *(const f16x8*)(&lds[4096 + row * 32 + quad * 8]);
    }
    #pragma unroll
    for (int nt = 0; nt < 4; nt++) {
      int row = wn * 64 + nt * 16 + lo;
      bh4[nt] = *(const f16x8*)(&lds[8192 + row * 32 + quad * 8]);
      bl4[nt] = *(const f16x8*)(&lds[12288 + row * 32 + quad * 8]);
    }
    #pragma unroll
    for (int mt = 0; mt < 4; mt++)
      #pragma unroll
      for (int nt = 0; nt < 4; nt++) {
        acc[mt][nt] = __builtin_amdgcn_mfma_f32_16x16x32_f16(ah[mt], bh4[nt], acc[mt][nt], 0, 0, 0);
        acc[mt][nt] = __builtin_amdgcn_mfma_f32_16x16x32_f16(ah[mt], bl4[nt], acc[mt][nt], 0, 0, 0);
        acc[mt][nt] = __builtin_amdgcn_mfma_f32_16x16x32_f16(al[mt], bh4[nt], acc[mt][nt], 0, 0, 0);
      }
    __syncthreads();
    #pragma unroll
    for (int j = 0; j < 4; j++) av[j] = nv[j];
  }

  #pragma unroll
  for (int nt = 0; nt < 4; nt++) {
    int col = wn * 64 + nt * 16 + lo;
    float bv = bias[col];
    #pragma unroll
    for (int mt = 0; mt < 4; mt++) {
      int rowb = P0 + wm * 64 + mt * 16 + quad * 4;
      #pragma unroll
      for (int r = 0; r < 4; r++)
        xout[(size_t)(rowb + r) * DLOI_ + col] = acc[mt][nt][r] + bv;
    }
  }
}

// ---------------------------------------------------------------------------
// K2: sample 32 pts/line, bilinear, maxpool by 4 -> feat as f16 hi/lo planes
// ---------------------------------------------------------------------------
__global__ __launch_bounds__(128) void k_sample(const float* __restrict__ x,
                                                const float* __restrict__ lines,
                                                f16* __restrict__ fh,
                                                f16* __restrict__ fl) {
  const int blk = blockIdx.x;   // b*L + l
  const int b = blk / L_;
  const int c = threadIdx.x;
  const float* ln = lines + (size_t)blk * 4;
  const float e0x = ln[0], e0y = ln[1], e1x = ln[2], e1y = ln[3];
  const float* xb = x + (size_t)b * HW_ * DLOI_;
  f16x8 vh, vl;
  for (int q = 0; q < NPTS1_; q++) {
    float m = -1e30f;
    #pragma unroll
    for (int r = 0; r < 4; r++) {
      int i = q * 4 + r;
      float lam = (float)i * (1.0f / 31.0f);
      float px = e0x * lam + e1x * (1.f - lam) - 0.5f;
      float py = e0y * lam + e1y * (1.f - lam) - 0.5f;
      float px0 = fminf(fmaxf(floorf(px), 0.f), 255.f);
      float py0 = fminf(fmaxf(floorf(py), 0.f), 255.f);
      float px1 = fminf(px0 + 1.f, 255.f);
      float py1 = fminf(py0 + 1.f, 255.f);
      int ix0 = (int)px0, iy0 = (int)py0, ix1 = (int)px1, iy1 = (int)py1;
      float w00 = (px1 - px) * (py1 - py);
      float w10 = (px - px0) * (py1 - py);
      float w01 = (px1 - px) * (py - py0);
      float w11 = (px - px0) * (py - py0);
      float v = w00 * xb[(size_t)(ix0 * W_ + iy0) * DLOI_ + c]
              + w10 * xb[(size_t)(ix1 * W_ + iy0) * DLOI_ + c]
              + w01 * xb[(size_t)(ix0 * W_ + iy1) * DLOI_ + c]
              + w11 * xb[(size_t)(ix1 * W_ + iy1) * DLOI_ + c];
      m = fmaxf(m, v);
    }
    f16 h = (f16)m;
    vh[q] = h;
    vl[q] = (f16)(m - (float)h);
  }
  *(f16x8*)(fh + (size_t)blk * DFC_ + c * 8) = vh;
  *(f16x8*)(fl + (size_t)blk * DFC_ + c * 8) = vl;
}

// ---------------------------------------------------------------------------
// K-tsplit: W[K][N] fp32 -> transposed f16 hi/lo planes Wt[N][K]
// ---------------------------------------------------------------------------
__global__ __launch_bounds__(256) void k_tsplit(const float* __restrict__ Wsrc,
                                                f16* __restrict__ Th,
                                                f16* __restrict__ Tl) {
  __shared__ float tile[32][33];
  const int bj = blockIdx.x, bi = blockIdx.y;
  const int tx = threadIdx.x & 31, ty = threadIdx.x >> 5;
  #pragma unroll
  for (int r = ty; r < 32; r += 8)
    tile[r][tx] = Wsrc[(size_t)(bi * 32 + r) * 1024 + bj * 32 + tx];
  __syncthreads();
  #pragma unroll
  for (int r = ty; r < 32; r += 8) {
    float v = tile[tx][r];
    f16 h = (f16)v;
    size_t o = (size_t)(bj * 32 + r) * 1024 + bi * 32 + tx;
    Th[o] = h;
    Tl[o] = (f16)(v - (float)h);
  }
}

// ---------------------------------------------------------------------------
// K3/K4: split-f16 3-product MFMA GEMM (MLP layers).
// XCD-swizzled 1-D grid (1280 blocks): xcd = bid&7 keeps the 8 n-tiles of a
// row-band consecutive on one XCD -> A band (512 KB) reused from that L2.
// SPLIT_OUT=true : store h1 as f16 hi/lo planes.
// SPLIT_OUT=false: fused head — per-block partial logits vs w3 (shuffle-
//                  reduced over the 16 lo-lanes, fixed order = deterministic).
// ---------------------------------------------------------------------------
template <bool SPLIT_OUT>
__global__ __launch_bounds__(256) void k_gemm_f16x3(
    const f16* __restrict__ Ah, const f16* __restrict__ Al,
    const f16* __restrict__ Bh, const f16* __restrict__ Bl,
    const float* __restrict__ bias,
    f16* __restrict__ Oh, f16* __restrict__ Ol,
    const float* __restrict__ w3, float* __restrict__ part) {
  constexpr int K = DFC_;
  __shared__ f16 lds[16384];
  const int bid = blockIdx.x;            // 0..1279
  const int xcd = bid & 7;
  const int t8  = bid >> 3;              // 0..159
  const int nb  = t8 & 7;
  const int rb  = xcd * 20 + (t8 >> 3);  // 0..159
  if (rb >= NBAND_) return;
  const int n0 = nb * 128;
  const int r0 = rb * 128;
  const int t = threadIdx.x;
  const int lane = t & 63, wave = t >> 6;
  const int quad = lane >> 4, lo = lane & 15;
  const int wm = wave >> 1, wn = wave & 1;

  const int srow = t >> 2;
  const int skb  = (t & 3) * 16;
  const char* gA_h = (const char*)Ah + (size_t)(r0 + srow) * (K * 2) + skb;
  const char* gA_l = (const char*)Al + (size_t)(r0 + srow) * (K * 2) + skb;
  const char* gB_h = (const char*)Bh + (size_t)(n0 + srow) * (K * 2) + skb;
  const char* gB_l = (const char*)Bl + (size_t)(n0 + srow) * (K * 2) + skb;
  char* lb = (char*)lds + t * 16;
  const size_t rstride64 = (size_t)64 * K * 2;

  f32x4 acc[4][4];
  #pragma unroll
  for (int mt = 0; mt < 4; mt++)
    #pragma unroll
    for (int nt = 0; nt < 4; nt++) acc[mt][nt] = (f32x4){0.f, 0.f, 0.f, 0.f};

  for (int kc = 0; kc < K / 32; kc++) {
    const size_t go = (size_t)kc * 64;
    gload16(gA_h + go,             lb);
    gload16(gA_h + rstride64 + go, lb + 4096);
    gload16(gA_l + go,             lb + 8192);
    gload16(gA_l + rstride64 + go, lb + 12288);
    gload16(gB_h + go,             lb + 16384);
    gload16(gB_h + rstride64 + go, lb + 20480);
    gload16(gB_l + go,             lb + 24576);
    gload16(gB_l + rstride64 + go, lb + 28672);
    __syncthreads();

    f16x8 ah[4], al[4], bh[4], bl[4];
    #pragma unroll
    for (int mt = 0; mt < 4; mt++) {
      int row = wm * 64 + mt * 16 + lo;
      ah[mt] = *(const f16x8*)(lds + row * 32 + quad * 8);
      al[mt] = *(const f16x8*)(lds + 4096 + row * 32 + quad * 8);
    }
    #pragma unroll
    for (int nt = 0; nt < 4; nt++) {
      int row = wn * 64 + nt * 16 + lo;
      bh[nt] = *(const f16x8*)(lds + 8192 + row * 32 + quad * 8);
      bl[nt] = *(const f16x8*)(lds + 12288 + row * 32 + quad * 8);
    }
    #pragma unroll
    for (int mt = 0; mt < 4; mt++)
      #pragma unroll
      for (int nt = 0; nt < 4; nt++) {
        acc[mt][nt] = __builtin_amdgcn_mfma_f32_16x16x32_f16(ah[mt], bh[nt], acc[mt][nt], 0, 0, 0);
        acc[mt][nt] = __builtin_amdgcn_mfma_f32_16x16x32_f16(ah[mt], bl[nt], acc[mt][nt], 0, 0, 0);
        acc[mt][nt] = __builtin_amdgcn_mfma_f32_16x16x32_f16(al[mt], bh[nt], acc[mt][nt], 0, 0, 0);
      }
    __syncthreads();
  }

  if (SPLIT_OUT) {
    #pragma unroll
    for (int mt = 0; mt < 4; mt++)
      #pragma unroll
      for (int nt = 0; nt < 4; nt++) {
        int col = n0 + wn * 64 + nt * 16 + lo;
        float bv = bias[col];
        int rowb = r0 + wm * 64 + mt * 16 + quad * 4;
        #pragma unroll
        for (int r = 0; r < 4; r++) {
          int row = rowb + r;
          if (row < M_) {
            float v = fmaxf(acc[mt][nt][r] + bv, 0.f);
            f16 h = (f16)v;
            Oh[(size_t)row * DFC_ + col] = h;
            Ol[(size_t)row * DFC_ + col] = (f16)(v - (float)h);
          }
        }
      }
  } else {
    // fused head: p[r][j] = sum over this block's 128 cols of relu(h2)*w3
    const int slot = nb * 2 + wn;   // 16 slots per row
    #pragma unroll
    for (int mt = 0; mt < 4; mt++) {
      float p[4][4];
      #pragma unroll
      for (int r = 0; r < 4; r++)
        #pragma unroll
        for (int j = 0; j < 4; j++) p[r][j] = 0.f;
      #pragma unroll
      for (int nt = 0; nt < 4; nt++) {
        int col = n0 + wn * 64 + nt * 16 + lo;
        float bv = bias[col];
        float4 wv = *(const float4*)(w3 + col * 4);
        #pragma unroll
        for (int r = 0; r < 4; r++) {
          float v = fmaxf(acc[mt][nt][r] + bv, 0.f);
          p[r][0] = fmaf(v, wv.x, p[r][0]);
          p[r][1] = fmaf(v, wv.y, p[r][1]);
          p[r][2] = fmaf(v, wv.z, p[r][2]);
          p[r][3] = fmaf(v, wv.w, p[r][3]);
        }
      }
      // reduce over the 16 lo-lanes (stays within the quad group)
      #pragma unroll
      for (int r = 0; r < 4; r++)
        #pragma unroll
        for (int j = 0; j < 4; j++) {
          p[r][j] += __shfl_xor(p[r][j], 1);
          p[r][j] += __shfl_xor(p[r][j], 2);
          p[r][j] += __shfl_xor(p[r][j], 4);
          p[r][j] += __shfl_xor(p[r][j], 8);
        }
      if (lo == 0) {
        int rowb = r0 + wm * 64 + mt * 16 + quad * 4;
        #pragma unroll
        for (int r = 0; r < 4; r++)
          *(float4*)(part + ((size_t)slot * MPAD_ + rowb + r) * 4) =
              make_float4(p[r][0], p[r][1], p[r][2], p[r][3]);
      }
    }
  }
}

// ---------------------------------------------------------------------------
// K5: sum 16 logit partials + b3, softmax, keep/argmax key.  1 thread/row.
// ---------------------------------------------------------------------------
__global__ __launch_bounds__(256) void k_head2(const float* __restrict__ part,
                                               const float* __restrict__ b3,
                                               float* __restrict__ s_out,
                                               int* __restrict__ key_out) {
  const int row = blockIdx.x * 256 + threadIdx.x;
  if (row >= M_) return;
  float l0 = b3[0], l1 = b3[1], l2 = b3[2], l3 = b3[3];
  #pragma unroll
  for (int sl = 0; sl < 16; sl++) {
    float4 p = *(const float4*)(part + ((size_t)sl * MPAD_ + row) * 4);
    l0 += p.x; l1 += p.y; l2 += p.z; l3 += p.w;
  }
  float mx = fmaxf(fmaxf(l0, l1), fmaxf(l2, l3));
  float e0 = expf(l0 - mx), e1 = expf(l1 - mx), e2 = expf(l2 - mx), e3 = expf(l3 - mx);
  float inv = 1.f / (e0 + e1 + e2 + e3);
  float s0 = e0 * inv, s1 = e1 * inv, s2 = e2 * inv, s3 = e3 * inv;
  *(float4*)(s_out + (size_t)row * 4) = make_float4(s0, s1, s2, s3);
  bool keep = ((s1 > 0.25f) || (s2 > 0.25f) || (s3 > 0.25f)) && (s0 < 0.25f);
  int am = 0; float best = s0;
  if (s1 > best) { best = s1; am = 1; }
  if (s2 > best) { best = s2; am = 2; }
  if (s3 > best) { best = s3; am = 3; }
  key_out[row] = keep ? am : -1;
}

// ---------------------------------------------------------------------------
// K6: per-batch stable counting sort (5 classes) + cyclic select.
// ---------------------------------------------------------------------------
__global__ __launch_bounds__(1024) void k_select(const int* __restrict__ key,
                                                 const float* __restrict__ lines,
                                                 const float* __restrict__ s,
                                                 float* __restrict__ out_lines,
                                                 float* __restrict__ out_score) {
  __shared__ int s_ord[L_];
  __shared__ int s_scan[1024];
  __shared__ int s_tot[5];
  const int b = blockIdx.x;
  const int t = threadIdx.x;
  const int base_l = t * 5;
  int cls[5];
  int c[5] = {0, 0, 0, 0, 0};
  #pragma unroll
  for (int i = 0; i < 5; i++) {
    int l = base_l + i;
    int cl = -1;
    if (l < L_) {
      int k = key[b * L_ + l];
      cl = (k < 0) ? 4 : (3 - k);
      c[cl]++;
    }
    cls[i] = cl;
  }
  int pf[5];
  for (int cc = 0; cc < 5; cc++) {
    s_scan[t] = c[cc];
    __syncthreads();
    for (int off = 1; off < 1024; off <<= 1) {
      int add = (t >= off) ? s_scan[t - off] : 0;
      __syncthreads();
      s_scan[t] += add;
      __syncthreads();
    }
    pf[cc] = s_scan[t] - c[cc];
    if (t == 1023) s_tot[cc] = s_scan[1023];
    __syncthreads();
  }
  int basec[5];
  basec[0] = 0;
  #pragma unroll
  for (int cc = 1; cc < 5; cc++) basec[cc] = basec[cc - 1] + s_tot[cc - 1];
  int run[5] = {0, 0, 0, 0, 0};
  #pragma unroll
  for (int i = 0; i < 5; i++) {
    if (cls[i] >= 0) {
      int cl = cls[i];
      int pos = basec[cl] + pf[cl] + run[cl];
      run[cl]++;
      s_ord[pos] = base_l + i;
    }
  }
  const int cnt = L_ - s_tot[4];
  __syncthreads();
  for (int j = t; j < NOUT_; j += 1024) {
    float4 lv = make_float4(0.f, 0.f, 0.f, 0.f);
    float4 sv = make_float4(0.f, 0.f, 0.f, 0.f);
    if (cnt > 0) {
      int idx = s_ord[j % cnt];
      lv = *(const float4*)(lines + (size_t)(b * L_ + idx) * 4);
      sv = *(const float4*)(s + (size_t)(b * L_ + idx) * 4);
    }
    *(float4*)(out_lines + (size_t)(b * NOUT_ + j) * 4) = lv;
    *(float4*)(out_score + (size_t)(b * NOUT_ + j) * 4) = sv;
  }
}

// ---------------------------------------------------------------------------
extern "C" void kernel_launch(void* const* d_in, const int* in_sizes, int n_in,
                              void* d_out, int out_size, void* d_ws, size_t ws_size,
                              hipStream_t stream) {
  const float* feature = (const float*)d_in[0];
  const float* lines   = (const float*)d_in[1];
  const float* fc1_w   = (const float*)d_in[2];
  const float* fc1_b   = (const float*)d_in[3];
  const float* w1      = (const float*)d_in[4];
  const float* b1      = (const float*)d_in[5];
  const float* w2      = (const float*)d_in[6];
  const float* b2      = (const float*)d_in[7];
  const float* w3      = (const float*)d_in[8];
  const float* b3      = (const float*)d_in[9];

  float* out_lines = (float*)d_out;
  float* out_score = out_lines + B_ * NOUT_ * 4;
  float* s_out     = out_score + B_ * NOUT_ * 4;

  // workspace layout (bytes):
  //   region X : [0, 134217728)         conv out x (fp32, channel-last);
  //              after k_sample -> h1h @0, h1l @41156608 (alias);
  //              logit partials @82313216 (+5144576, alias, live in GEMM2+)
  //   fh       : [134217728, +41156608) feat hi  (MPAD x 1024 f16)
  //   fl       : [175374336, +41156608) feat lo
  //   wt       : [216530944, +4*2097152)  wt1h wt1l wt2h wt2l
  //   keys     : [224919552, +80000)
  //   wc       : [224999552, +2*65536)  fc1_w f16 hi/lo planes
  char* ws = (char*)d_ws;
  float* x    = (float*)(ws);
  f16*   h1h  = (f16*)(ws);
  f16*   h1l  = (f16*)(ws + 41156608ull);
  float* part = (float*)(ws + 82313216ull);
  f16*   fh   = (f16*)(ws + 134217728ull);
  f16*   fl   = (f16*)(ws + 134217728ull + 41156608ull);
  f16*   wt1h = (f16*)(ws + 216530944ull);
  f16*   wt1l = (f16*)(ws + 216530944ull + 2097152ull);
  f16*   wt2h = (f16*)(ws + 216530944ull + 2ull * 2097152ull);
  f16*   wt2l = (f16*)(ws + 216530944ull + 3ull * 2097152ull);
  int*   keys = (int*)(ws + 224919552ull);
  f16*   wc_h = (f16*)(ws + 224999552ull);
  f16*   wc_l = (f16*)(ws + 224999552ull + 65536ull);

  k_wsplit<<<dim3(32), 256, 0, stream>>>(fc1_w, wc_h, wc_l);
  k_tsplit<<<dim3(32, 32), 256, 0, stream>>>(w1, wt1h, wt1l);
  k_tsplit<<<dim3(32, 32), 256, 0, stream>>>(w2, wt2h, wt2l);
  k_conv_mfma<<<dim3((B_ * HW_) / 128), 256, 0, stream>>>(feature, wc_h, wc_l, fc1_b, x);
  k_sample<<<dim3(M_), 128, 0, stream>>>(x, lines, fh, fl);
  k_gemm_f16x3<true><<<dim3(1280), 256, 0, stream>>>(
      fh, fl, wt1h, wt1l, b1, h1h, h1l, nullptr, nullptr);
  k_gemm_f16x3<false><<<dim3(1280), 256, 0, stream>>>(
      h1h, h1l, wt2h, wt2l, b2, nullptr, nullptr, w3, part);
  k_head2<<<dim3((M_ + 255) / 256), 256, 0, stream>>>(part, b3, s_out, keys);
  k_select<<<dim3(B_), 1024, 0, stream>>>(keys, lines, s_out, out_lines, out_score);
}